// Round 1
// baseline (746.411 us; speedup 1.0000x reference)
//
#include <hip/hip_runtime.h>
#include <cstddef>

namespace {
constexpr int kB = 16;
constexpr int kN = 2048;
constexpr int kD = 256;   // D_IN
constexpr int kC = 32;
constexpr int kH = 64;
constexpr int kHeads = 4;
constexpr int kKD = 64;

// workspace offsets (in floats)
constexpr size_t OFF_XPART = 0;            // [B,16,D]    = 65536
constexpr size_t OFF_Y     = 65536;        // [B,C,D]     = 131072
constexpr size_t OFF_CS    = 196608;       // [B,C]       = 512
constexpr size_t OFF_V     = 197120;       // [B,C,H]     = 32768
constexpr size_t OFF_WV    = 229888;       // [B,C,D]     = 131072
constexpr size_t OFF_BV    = 360960;       // [B,C]       = 512
constexpr size_t OFF_BB    = 361472;       // [B,N,C]     = 1048576
constexpr size_t OFF_CTX   = 1410048;      // [B,C,HEADS,KD] = 524288
}  // namespace

// ---- K1: partial sums of x over n: xpart[b,j,d] = sum_{n in chunk j} x[b,n,d]
__global__ __launch_bounds__(256) void k_xpart(const float* __restrict__ x,
                                               float* __restrict__ xpart) {
  const int b = blockIdx.x, j = blockIdx.y, d = threadIdx.x;
  const float* xp = x + ((size_t)b * kN + (size_t)j * 128) * kD + d;
  float s = 0.f;
#pragma unroll 8
  for (int n = 0; n < 128; ++n) s += xp[(size_t)n * kD];
  xpart[((size_t)b * 16 + j) * kD + d] = s;
}

// ---- K2/K4/K6: s = y·W[c] + csum*b_caps[c]; v = squash(s); optionally Wv = W[c]·v, bv = b_caps[c]·v
// mode 0: y := (sum_j xpart)/C, csum := N/C   (routing iteration 0, uniform coupling)
// mode 1: y,csum read from workspace (accumulated by k_route)
__global__ __launch_bounds__(64) void k_sv(
    const float* __restrict__ W, const float* __restrict__ b_caps,
    const float* __restrict__ xpart, const float* __restrict__ y,
    const float* __restrict__ csum, float* __restrict__ v,
    float* __restrict__ Wv, float* __restrict__ bv,
    const int mode, const int computeWv) {
  const int bc = blockIdx.x, b = bc >> 5, c = bc & 31;
  const int h = threadIdx.x;  // 64 threads = 1 wave
  __shared__ float yL[kD];
  __shared__ float vL[kH];
  float cs;
  if (mode == 0) {
    for (int d = h; d < kD; d += 64) {
      float s = 0.f;
#pragma unroll
      for (int j = 0; j < 16; ++j) s += xpart[((size_t)b * 16 + j) * kD + d];
      yL[d] = s * (1.f / (float)kC);
    }
    cs = (float)kN / (float)kC;
  } else {
    for (int d = h; d < kD; d += 64) yL[d] = y[(size_t)bc * kD + d];
    cs = csum[bc];
  }
  __syncthreads();
  const float* Wc = W + (size_t)c * kD * kH;
  float s = 0.f;
#pragma unroll 8
  for (int d = 0; d < kD; ++d) s = fmaf(yL[d], Wc[(size_t)d * kH + h], s);
  const float bch = b_caps[c * kH + h];
  s += cs * bch;
  // squash over h (one 64-lane wave)
  float s2 = s * s;
#pragma unroll
  for (int off = 32; off; off >>= 1) s2 += __shfl_xor(s2, off, 64);
  const float scale = s2 / (1.f + s2) * rsqrtf(s2 + 1e-7f);
  const float vh = scale * s;
  v[(size_t)bc * kH + h] = vh;
  if (computeWv) {
    float bvp = bch * vh;
#pragma unroll
    for (int off = 32; off; off >>= 1) bvp += __shfl_xor(bvp, off, 64);
    if (h == 0) bv[bc] = bvp;
    vL[h] = vh;
    __syncthreads();
    for (int d = h; d < kD; d += 64) {
      float acc = 0.f;
#pragma unroll
      for (int hh = 0; hh < kH; ++hh) acc = fmaf(Wc[(size_t)d * kH + hh], vL[hh], acc);
      Wv[(size_t)bc * kD + d] = acc;
    }
  }
}

// ---- K3/K5: fused routing pass.  Per (b, chunk of 64 n):
//   a[c]   = x[n]·Wv[b,c] + bv[b,c]          (agreement)
//   bnew   = bold + a   (bold=0 and store on iter 0; load on iter 1)
//   p      = softmax_c(bnew)
//   y[c,:]+= p[c]*x[n],  csum[c] += p[c]     (atomically flushed at end)
__global__ __launch_bounds__(256) void k_route(
    const float* __restrict__ x, const float* __restrict__ Wv,
    const float* __restrict__ bv, float* __restrict__ bbuf,
    float* __restrict__ y, float* __restrict__ csum, const int iter) {
  const int b = blockIdx.x, chunk = blockIdx.y;
  const int t = threadIdx.x;
  const int c = t & 31, seg = t >> 5;  // lane's capsule + 32-wide d-segment
  __shared__ float xs[kD];
  __shared__ float aL[8][32];
  __shared__ float soft[32];
  __shared__ float bvL[32];

  float wv[32];
  {
    const float4* p = reinterpret_cast<const float4*>(
        Wv + ((size_t)(b * kC + c)) * kD + seg * 32);
#pragma unroll
    for (int j = 0; j < 8; ++j) {
      float4 q = p[j];
      wv[4 * j] = q.x; wv[4 * j + 1] = q.y; wv[4 * j + 2] = q.z; wv[4 * j + 3] = q.w;
    }
  }
  if (t < 32) bvL[t] = bv[b * kC + t];
  float yreg[32];
#pragma unroll
  for (int i = 0; i < 32; ++i) yreg[i] = 0.f;
  float csreg = 0.f;

  const int n0 = chunk * 64;
  float xv = x[((size_t)b * kN + n0) * kD + t];
  for (int nn = 0; nn < 64; ++nn) {
    xs[t] = xv;
    if (nn < 63) xv = x[((size_t)b * kN + n0 + nn + 1) * kD + t];  // prefetch
    __syncthreads();  // B: xs visible
    float xr[32];
    {
      const float4* p = reinterpret_cast<const float4*>(xs + seg * 32);
#pragma unroll
      for (int j = 0; j < 8; ++j) {
        float4 q = p[j];  // same addr across the 32 lanes of a half-wave: LDS broadcast
        xr[4 * j] = q.x; xr[4 * j + 1] = q.y; xr[4 * j + 2] = q.z; xr[4 * j + 3] = q.w;
      }
    }
    float ap = 0.f;
#pragma unroll
    for (int i = 0; i < 32; ++i) ap = fmaf(wv[i], xr[i], ap);
    aL[seg][c] = ap;  // bank = c: conflict-free
    __syncthreads();  // C: aL visible
    if (t < 32) {
      float a = bvL[t];
#pragma unroll
      for (int j = 0; j < 8; ++j) a += aL[j][t];
      const size_t bidx = ((size_t)b * kN + n0 + nn) * kC + t;
      if (iter) a += bbuf[bidx];
      else bbuf[bidx] = a;
      float m = a;
#pragma unroll
      for (int off = 16; off; off >>= 1) m = fmaxf(m, __shfl_xor(m, off, 64));
      const float e = __expf(a - m);
      float ssum = e;
#pragma unroll
      for (int off = 16; off; off >>= 1) ssum += __shfl_xor(ssum, off, 64);
      const float sm = e / ssum;
      soft[t] = sm;
      csreg += sm;
    }
    __syncthreads();  // D: soft visible
    const float sc = soft[c];
#pragma unroll
    for (int i = 0; i < 32; ++i) yreg[i] = fmaf(sc, xr[i], yreg[i]);
  }
  float* yp = y + ((size_t)(b * kC + c)) * kD + seg * 32;
#pragma unroll
  for (int i = 0; i < 32; ++i) atomicAdd(yp + i, yreg[i]);
  if (t < 32) atomicAdd(csum + b * kC + t, csreg);
}

// ---- K7: per (b, head) self-attention over the 32 capsules; writes ctx[b,qc,head,d]
__global__ __launch_bounds__(256) void k_mha(
    const float* __restrict__ routed, const float* __restrict__ Wq,
    const float* __restrict__ bq, const float* __restrict__ Wk,
    const float* __restrict__ bk, const float* __restrict__ Wvp,
    const float* __restrict__ bvp, float* __restrict__ ctx) {
  const int b = blockIdx.x, head = blockIdx.y, t = threadIdx.x;
  __shared__ float rL[kC * kH];
  __shared__ float qL[kC * kKD];
  __shared__ float kL[kC * kKD];
  __shared__ float vL[kC * kKD];
  __shared__ float sc[kC][kC];
  for (int i = t; i < kC * kH; i += 256) rL[i] = routed[(size_t)b * kC * kH + i];
  __syncthreads();
  for (int e = t; e < kC * kKD; e += 256) {
    const int cc = e >> 6, kk = e & 63;
    float aq = bq[head * kKD + kk];
    float ak = bk[head * kKD + kk];
    float av = bvp[head * kKD + kk];
#pragma unroll 8
    for (int hh = 0; hh < kH; ++hh) {
      const float r = rL[cc * kH + hh];
      const int wi = (hh * kHeads + head) * kKD + kk;
      aq = fmaf(r, Wq[wi], aq);
      ak = fmaf(r, Wk[wi], ak);
      av = fmaf(r, Wvp[wi], av);
    }
    qL[e] = aq; kL[e] = ak; vL[e] = av;
  }
  __syncthreads();
  for (int e = t; e < kC * kC; e += 256) {
    const int qc = e >> 5, kc = e & 31;
    float s = 0.f;
#pragma unroll 8
    for (int d = 0; d < kKD; ++d) s = fmaf(qL[qc * kKD + d], kL[kc * kKD + d], s);
    sc[qc][kc] = s * 0.125f;  // 1/sqrt(64)
  }
  __syncthreads();
  if (t < kC) {
    float m = -1e30f;
#pragma unroll
    for (int kc = 0; kc < kC; ++kc) m = fmaxf(m, sc[t][kc]);
    float ssum = 0.f;
#pragma unroll
    for (int kc = 0; kc < kC; ++kc) {
      const float e2 = __expf(sc[t][kc] - m);
      sc[t][kc] = e2;
      ssum += e2;
    }
    const float inv = 1.f / ssum;
#pragma unroll
    for (int kc = 0; kc < kC; ++kc) sc[t][kc] *= inv;
  }
  __syncthreads();
  for (int e = t; e < kC * kKD; e += 256) {
    const int qc = e >> 6, d = e & 63;
    float s = 0.f;
#pragma unroll 8
    for (int kc = 0; kc < kC; ++kc) s = fmaf(sc[qc][kc], vL[kc * kKD + d], s);
    ctx[(((size_t)b * kC + qc) * kHeads + head) * kKD + d] = s;
  }
}

// ---- K8: out-proj + residual + LayerNorm + squash*gamma, per (b,c), one wave
__global__ __launch_bounds__(64) void k_final(
    const float* __restrict__ ctx, const float* __restrict__ Wo,
    const float* __restrict__ bo, const float* __restrict__ routed,
    const float* __restrict__ ln_g, const float* __restrict__ ln_b,
    const float* __restrict__ gamma, float* __restrict__ out) {
  const int bc = blockIdx.x, h = threadIdx.x;
  __shared__ float cL[kHeads * kKD];
  for (int i = h; i < kHeads * kKD; i += 64) cL[i] = ctx[(size_t)bc * (kHeads * kKD) + i];
  __syncthreads();
  float s = bo[h];
#pragma unroll 8
  for (int nd = 0; nd < kHeads * kKD; ++nd) s = fmaf(cL[nd], Wo[(size_t)nd * kH + h], s);
  const float yv = s + routed[(size_t)bc * kH + h];
  float mu = yv;
#pragma unroll
  for (int off = 32; off; off >>= 1) mu += __shfl_xor(mu, off, 64);
  mu *= (1.f / (float)kH);
  const float dv = yv - mu;
  float var = dv * dv;
#pragma unroll
  for (int off = 32; off; off >>= 1) var += __shfl_xor(var, off, 64);
  var *= (1.f / (float)kH);
  const float nrm = dv * rsqrtf(var + 1e-3f) * ln_g[h] + ln_b[h];
  float s2 = nrm * nrm;
#pragma unroll
  for (int off = 32; off; off >>= 1) s2 += __shfl_xor(s2, off, 64);
  const float scale = s2 / (1.f + s2) * rsqrtf(s2 + 1e-7f);
  out[(size_t)bc * kH + h] = scale * nrm * gamma[0];
}

extern "C" void kernel_launch(void* const* d_in, const int* in_sizes, int n_in,
                              void* d_out, int out_size, void* d_ws, size_t ws_size,
                              hipStream_t stream) {
  (void)in_sizes; (void)n_in; (void)out_size; (void)ws_size;
  const float* x      = (const float*)d_in[0];
  const float* W      = (const float*)d_in[1];
  const float* b_caps = (const float*)d_in[2];
  const float* gamma  = (const float*)d_in[3];
  const float* Wq     = (const float*)d_in[4];
  const float* bq     = (const float*)d_in[5];
  const float* Wk     = (const float*)d_in[6];
  const float* bk     = (const float*)d_in[7];
  const float* Wv_in  = (const float*)d_in[8];
  const float* bv_in  = (const float*)d_in[9];
  const float* Wo     = (const float*)d_in[10];
  const float* bo     = (const float*)d_in[11];
  const float* ln_g   = (const float*)d_in[12];
  const float* ln_b   = (const float*)d_in[13];
  float* out = (float*)d_out;
  float* ws  = (float*)d_ws;

  float* xpart = ws + OFF_XPART;
  float* y     = ws + OFF_Y;
  float* cs    = ws + OFF_CS;
  float* v     = ws + OFF_V;
  float* Wv    = ws + OFF_WV;
  float* bv    = ws + OFF_BV;
  float* bb    = ws + OFF_BB;
  float* ctx   = ws + OFF_CTX;

  // iter 0: uniform coupling — needs only column sums of x
  k_xpart<<<dim3(kB, 16), 256, 0, stream>>>(x, xpart);
  k_sv<<<kB * kC, 64, 0, stream>>>(W, b_caps, xpart, y, cs, v, Wv, bv, 0, 1);

  hipMemsetAsync(y, 0, (size_t)kB * kC * kD * sizeof(float), stream);
  hipMemsetAsync(cs, 0, (size_t)kB * kC * sizeof(float), stream);
  k_route<<<dim3(kB, 32), 256, 0, stream>>>(x, Wv, bv, bb, y, cs, 0);
  k_sv<<<kB * kC, 64, 0, stream>>>(W, b_caps, xpart, y, cs, v, Wv, bv, 1, 1);

  hipMemsetAsync(y, 0, (size_t)kB * kC * kD * sizeof(float), stream);
  hipMemsetAsync(cs, 0, (size_t)kB * kC * sizeof(float), stream);
  k_route<<<dim3(kB, 32), 256, 0, stream>>>(x, Wv, bv, bb, y, cs, 1);
  k_sv<<<kB * kC, 64, 0, stream>>>(W, b_caps, xpart, y, cs, v, Wv, bv, 1, 0);

  // v now holds routed [B,C,H]
  k_mha<<<dim3(kB, kHeads), 256, 0, stream>>>(v, Wq, bq, Wk, bk, Wv_in, bv_in, ctx);
  k_final<<<kB * kC, 64, 0, stream>>>(ctx, Wo, bo, v, ln_g, ln_b, gamma, out);
}

// Round 2
// 326.861 us; speedup vs baseline: 2.2836x; 2.2836x over previous
//
#include <hip/hip_runtime.h>
#include <cstddef>

namespace {
constexpr int kB = 16;
constexpr int kN = 2048;
constexpr int kD = 256;   // D_IN
constexpr int kC = 32;
constexpr int kH = 64;
constexpr int kHeads = 4;
constexpr int kKD = 64;
constexpr int kChunks = 32;     // n-chunks per b (64 rows each)
constexpr int kRowsPerChunk = kN / kChunks;  // 64
constexpr int kTileR = 32;      // rows per LDS tile
constexpr int kTiles = kRowsPerChunk / kTileR;  // 2

// workspace offsets (floats). Small buffers first; ypart last so the
// atomic fallback never needs it.
constexpr size_t OFF_XPART = 0;                      // [B,16,D]        65536
constexpr size_t OFF_V     = OFF_XPART + 65536;      // [B,C,H]         32768
constexpr size_t OFF_WV    = OFF_V + 32768;          // [B,C,D]        131072
constexpr size_t OFF_BV    = OFF_WV + 131072;        // [B,C]             512
constexpr size_t OFF_CTX   = OFF_BV + 512;           // [B,C,HEADS,KD] 524288
constexpr size_t OFF_Y     = OFF_CTX + 524288;       // [B,C,D]        131072 (atomic path)
constexpr size_t OFF_CS    = OFF_Y + 131072;         // [B,C]             512
constexpr size_t OFF_CSP   = OFF_CS + 512;           // [B,chunks,C]    16384
constexpr size_t OFF_YP    = OFF_CSP + 16384;        // [B,chunks,C,D] 4194304
constexpr size_t WS_NEED_PARTIAL = (OFF_YP + 4194304) * sizeof(float);
}  // namespace

// ---- K1: partial sums of x over n: xpart[b,j,d] = sum_{n in chunk j} x[b,n,d]
__global__ __launch_bounds__(256) void k_xpart(const float* __restrict__ x,
                                               float* __restrict__ xpart) {
  const int b = blockIdx.x, j = blockIdx.y, d = threadIdx.x;
  const float* xp = x + ((size_t)b * kN + (size_t)j * 128) * kD + d;
  float s = 0.f;
#pragma unroll 8
  for (int n = 0; n < 128; ++n) s += xp[(size_t)n * kD];
  xpart[((size_t)b * 16 + j) * kD + d] = s;
}

// ---- k_sv: s = y·W[c] + csum*b_caps[c]; v = squash(s);
//  computeWv: Wv (+)= W[c]·v, bv (+)= b_caps[c]·v   (accWv selects += vs =)
//  mode 0: y from xpart/C (uniform routing iter 0). mode 1: y from route output.
//  npart>0: reduce per-chunk partials instead of reading y/cs.
__global__ __launch_bounds__(64) void k_sv(
    const float* __restrict__ W, const float* __restrict__ b_caps,
    const float* __restrict__ xpart, const float* __restrict__ y,
    const float* __restrict__ csum, const float* __restrict__ ypart,
    const float* __restrict__ cspart, float* __restrict__ v,
    float* __restrict__ Wv, float* __restrict__ bv,
    const int mode, const int computeWv, const int accWv, const int npart) {
  const int bc = blockIdx.x, b = bc >> 5, c = bc & 31;
  const int h = threadIdx.x;  // one wave
  __shared__ float yL[kD];
  __shared__ float vL[kH];
  float cs;
  if (mode == 0) {
    for (int d = h; d < kD; d += 64) {
      float s = 0.f;
#pragma unroll
      for (int j = 0; j < 16; ++j) s += xpart[((size_t)b * 16 + j) * kD + d];
      yL[d] = s * (1.f / (float)kC);
    }
    cs = (float)kN / (float)kC;
  } else if (npart > 0) {
    for (int d = h; d < kD; d += 64) {
      float s = 0.f;
#pragma unroll 8
      for (int ch = 0; ch < kChunks; ++ch)
        s += ypart[(((size_t)b * kChunks + ch) * kC + c) * kD + d];
      yL[d] = s;
    }
    float s = 0.f;
#pragma unroll 8
    for (int ch = 0; ch < kChunks; ++ch)
      s += cspart[((size_t)b * kChunks + ch) * kC + c];
    cs = s;
  } else {
    for (int d = h; d < kD; d += 64) yL[d] = y[(size_t)bc * kD + d];
    cs = csum[bc];
  }
  __syncthreads();
  const float* Wc = W + (size_t)c * kD * kH;
  float s = 0.f;
#pragma unroll 8
  for (int d = 0; d < kD; ++d) s = fmaf(yL[d], Wc[(size_t)d * kH + h], s);
  const float bch = b_caps[c * kH + h];
  s += cs * bch;
  float s2 = s * s;
#pragma unroll
  for (int off = 32; off; off >>= 1) s2 += __shfl_xor(s2, off, 64);
  const float scale = s2 / (1.f + s2) * rsqrtf(s2 + 1e-7f);
  const float vh = scale * s;
  v[(size_t)bc * kH + h] = vh;
  if (computeWv) {
    float bvp = bch * vh;
#pragma unroll
    for (int off = 32; off; off >>= 1) bvp += __shfl_xor(bvp, off, 64);
    if (h == 0) bv[bc] = accWv ? (bv[bc] + bvp) : bvp;
    vL[h] = vh;
    __syncthreads();
    for (int d = h; d < kD; d += 64) {
      float acc = 0.f;
#pragma unroll
      for (int hh = 0; hh < kH; ++hh) acc = fmaf(Wc[(size_t)d * kH + hh], vL[hh], acc);
      Wv[(size_t)bc * kD + d] = accWv ? (Wv[(size_t)bc * kD + d] + acc) : acc;
    }
  }
}

// ---- k_route: tiled routing pass. Block = (b, chunk of 64 rows); 2 tiles of 32.
// Per tile: stage x[32][256] in LDS; A[r,c] = x[r]·Wv[c] + bv[c] (Wv in regs,
// LDS broadcast reads); softmax over c per row; y[c,:] += p[r,c]*x[r,:].
// Flush: per-chunk partial store (usePart) or atomics.
__global__ __launch_bounds__(256) void k_route(
    const float* __restrict__ x, const float* __restrict__ Wv,
    const float* __restrict__ bv, float* __restrict__ y,
    float* __restrict__ csum, float* __restrict__ ypart,
    float* __restrict__ cspart, const int usePart) {
  const int b = blockIdx.x, chunk = blockIdx.y;
  const int t = threadIdx.x;
  const int c = t & 31, seg = t >> 5;   // capsule, 32-wide d-segment (0..7)
  const int w = t >> 6;                 // wave (0..3)
  __shared__ float xs[kTileR][kD];      // 32 KB
  __shared__ float aL[4][kTileR][kC];   // 16 KB  seg-pair partial logits
  __shared__ float pL[kTileR][kC];      // 4 KB
  __shared__ float csL[8][kC];          // 1 KB

  // Wv slice for (c, seg) in registers
  float wv[32];
  {
    const float4* p = reinterpret_cast<const float4*>(
        Wv + ((size_t)(b * kC + c)) * kD + seg * 32);
#pragma unroll
    for (int j = 0; j < 8; ++j) {
      float4 q = p[j];
      wv[4 * j] = q.x; wv[4 * j + 1] = q.y; wv[4 * j + 2] = q.z; wv[4 * j + 3] = q.w;
    }
  }
  const float bvreg = bv[b * kC + c];
  float yreg[32];
#pragma unroll
  for (int i = 0; i < 32; ++i) yreg[i] = 0.f;
  float csreg = 0.f;

  const int n0 = chunk * kRowsPerChunk;
  // prologue: load tile 0 into regs
  float4 xf[8];
  {
    const float4* xg = reinterpret_cast<const float4*>(
        x + ((size_t)b * kN + n0) * kD);
#pragma unroll
    for (int j = 0; j < 8; ++j) xf[j] = xg[t + 256 * j];
  }

#pragma unroll
  for (int tile = 0; tile < kTiles; ++tile) {
    __syncthreads();  // previous tile's xs readers done
    {
      float4* xs4 = reinterpret_cast<float4*>(&xs[0][0]);
#pragma unroll
      for (int j = 0; j < 8; ++j) xs4[t + 256 * j] = xf[j];
    }
    __syncthreads();  // xs visible
    if (tile + 1 < kTiles) {
      // prefetch next tile; drains at the next barrier, overlapped with A phase
      const float4* xg = reinterpret_cast<const float4*>(
          x + ((size_t)b * kN + n0 + (tile + 1) * kTileR) * kD);
#pragma unroll
      for (int j = 0; j < 8; ++j) xf[j] = xg[t + 256 * j];
    }
    // ---- A phase: partial logits over this thread's 32-wide d-slice
#pragma unroll
    for (int g = 0; g < 4; ++g) {
      float ar[8];
#pragma unroll
      for (int r8 = 0; r8 < 8; ++r8) {
        const int r = g * 8 + r8;
        const float4* xv = reinterpret_cast<const float4*>(&xs[r][seg * 32]);
        float acc = 0.f;
#pragma unroll
        for (int j = 0; j < 8; ++j) {
          float4 q = xv[j];  // broadcast within half-wave
          acc = fmaf(wv[4 * j], q.x, acc);
          acc = fmaf(wv[4 * j + 1], q.y, acc);
          acc = fmaf(wv[4 * j + 2], q.z, acc);
          acc = fmaf(wv[4 * j + 3], q.w, acc);
        }
        ar[r8] = acc;
      }
#pragma unroll
      for (int r8 = 0; r8 < 8; ++r8) {
        ar[r8] += __shfl_xor(ar[r8], 32);  // combine seg pair within wave
        if ((t & 32) == 0) aL[w][g * 8 + r8][c] = ar[r8];
      }
    }
    __syncthreads();  // aL visible
    // ---- softmax: thread (c, seg) handles rows seg*4+k
#pragma unroll
    for (int k = 0; k < 4; ++k) {
      const int r = seg * 4 + k;
      float L = bvreg;
#pragma unroll
      for (int j = 0; j < 4; ++j) L += aL[j][r][c];
      float m = L;
#pragma unroll
      for (int off = 16; off; off >>= 1) m = fmaxf(m, __shfl_xor(m, off, 64));
      const float e = __expf(L - m);
      float ssum = e;
#pragma unroll
      for (int off = 16; off; off >>= 1) ssum += __shfl_xor(ssum, off, 64);
      const float p = e / ssum;
      pL[r][c] = p;
      csreg += p;
    }
    __syncthreads();  // pL visible
    // ---- accumulate y
#pragma unroll 4
    for (int r = 0; r < kTileR; ++r) {
      const float p = pL[r][c];
      const float4* xv = reinterpret_cast<const float4*>(&xs[r][seg * 32]);
#pragma unroll
      for (int j = 0; j < 8; ++j) {
        float4 q = xv[j];
        yreg[4 * j] = fmaf(p, q.x, yreg[4 * j]);
        yreg[4 * j + 1] = fmaf(p, q.y, yreg[4 * j + 1]);
        yreg[4 * j + 2] = fmaf(p, q.z, yreg[4 * j + 2]);
        yreg[4 * j + 3] = fmaf(p, q.w, yreg[4 * j + 3]);
      }
    }
  }
  // ---- flush
  csL[seg][c] = csreg;
  __syncthreads();
  if (usePart) {
    float4* yp = reinterpret_cast<float4*>(
        ypart + (((size_t)b * kChunks + chunk) * kC + c) * kD + seg * 32);
#pragma unroll
    for (int j = 0; j < 8; ++j) {
      float4 q;
      q.x = yreg[4 * j]; q.y = yreg[4 * j + 1];
      q.z = yreg[4 * j + 2]; q.w = yreg[4 * j + 3];
      yp[j] = q;
    }
    if (t < 32) {
      float s = 0.f;
#pragma unroll
      for (int j = 0; j < 8; ++j) s += csL[j][t];
      cspart[((size_t)b * kChunks + chunk) * kC + t] = s;
    }
  } else {
    float* yp = y + ((size_t)(b * kC + c)) * kD + seg * 32;
#pragma unroll
    for (int i = 0; i < 32; ++i) atomicAdd(yp + i, yreg[i]);
    if (t < 32) {
      float s = 0.f;
#pragma unroll
      for (int j = 0; j < 8; ++j) s += csL[j][t];
      atomicAdd(csum + b * kC + t, s);
    }
  }
}

// ---- k_mha: per (b, head) self-attention over the 32 capsules
__global__ __launch_bounds__(256) void k_mha(
    const float* __restrict__ routed, const float* __restrict__ Wq,
    const float* __restrict__ bq, const float* __restrict__ Wk,
    const float* __restrict__ bk, const float* __restrict__ Wvp,
    const float* __restrict__ bvp, float* __restrict__ ctx) {
  const int b = blockIdx.x, head = blockIdx.y, t = threadIdx.x;
  __shared__ float rL[kC * kH];
  __shared__ float qL[kC * kKD];
  __shared__ float kL[kC * kKD];
  __shared__ float vL[kC * kKD];
  __shared__ float sc[kC][kC];
  for (int i = t; i < kC * kH; i += 256) rL[i] = routed[(size_t)b * kC * kH + i];
  __syncthreads();
  for (int e = t; e < kC * kKD; e += 256) {
    const int cc = e >> 6, kk = e & 63;
    float aq = bq[head * kKD + kk];
    float ak = bk[head * kKD + kk];
    float av = bvp[head * kKD + kk];
#pragma unroll 8
    for (int hh = 0; hh < kH; ++hh) {
      const float r = rL[cc * kH + hh];
      const int wi = (hh * kHeads + head) * kKD + kk;
      aq = fmaf(r, Wq[wi], aq);
      ak = fmaf(r, Wk[wi], ak);
      av = fmaf(r, Wvp[wi], av);
    }
    qL[e] = aq; kL[e] = ak; vL[e] = av;
  }
  __syncthreads();
  for (int e = t; e < kC * kC; e += 256) {
    const int qc = e >> 5, kc = e & 31;
    float s = 0.f;
#pragma unroll 8
    for (int d = 0; d < kKD; ++d) s = fmaf(qL[qc * kKD + d], kL[kc * kKD + d], s);
    sc[qc][kc] = s * 0.125f;
  }
  __syncthreads();
  if (t < kC) {
    float m = -1e30f;
#pragma unroll
    for (int kc = 0; kc < kC; ++kc) m = fmaxf(m, sc[t][kc]);
    float ssum = 0.f;
#pragma unroll
    for (int kc = 0; kc < kC; ++kc) {
      const float e2 = __expf(sc[t][kc] - m);
      sc[t][kc] = e2;
      ssum += e2;
    }
    const float inv = 1.f / ssum;
#pragma unroll
    for (int kc = 0; kc < kC; ++kc) sc[t][kc] *= inv;
  }
  __syncthreads();
  for (int e = t; e < kC * kKD; e += 256) {
    const int qc = e >> 6, d = e & 63;
    float s = 0.f;
#pragma unroll 8
    for (int kc = 0; kc < kC; ++kc) s = fmaf(sc[qc][kc], vL[kc * kKD + d], s);
    ctx[(((size_t)b * kC + qc) * kHeads + head) * kKD + d] = s;
  }
}

// ---- k_final: out-proj + residual + LayerNorm + squash*gamma
__global__ __launch_bounds__(64) void k_final(
    const float* __restrict__ ctx, const float* __restrict__ Wo,
    const float* __restrict__ bo, const float* __restrict__ routed,
    const float* __restrict__ ln_g, const float* __restrict__ ln_b,
    const float* __restrict__ gamma, float* __restrict__ out) {
  const int bc = blockIdx.x, h = threadIdx.x;
  __shared__ float cL[kHeads * kKD];
  for (int i = h; i < kHeads * kKD; i += 64) cL[i] = ctx[(size_t)bc * (kHeads * kKD) + i];
  __syncthreads();
  float s = bo[h];
#pragma unroll 8
  for (int nd = 0; nd < kHeads * kKD; ++nd) s = fmaf(cL[nd], Wo[(size_t)nd * kH + h], s);
  const float yv = s + routed[(size_t)bc * kH + h];
  float mu = yv;
#pragma unroll
  for (int off = 32; off; off >>= 1) mu += __shfl_xor(mu, off, 64);
  mu *= (1.f / (float)kH);
  const float dv = yv - mu;
  float var = dv * dv;
#pragma unroll
  for (int off = 32; off; off >>= 1) var += __shfl_xor(var, off, 64);
  var *= (1.f / (float)kH);
  const float nrm = dv * rsqrtf(var + 1e-3f) * ln_g[h] + ln_b[h];
  float s2 = nrm * nrm;
#pragma unroll
  for (int off = 32; off; off >>= 1) s2 += __shfl_xor(s2, off, 64);
  const float scale = s2 / (1.f + s2) * rsqrtf(s2 + 1e-7f);
  out[(size_t)bc * kH + h] = scale * nrm * gamma[0];
}

extern "C" void kernel_launch(void* const* d_in, const int* in_sizes, int n_in,
                              void* d_out, int out_size, void* d_ws, size_t ws_size,
                              hipStream_t stream) {
  (void)in_sizes; (void)n_in; (void)out_size;
  const float* x      = (const float*)d_in[0];
  const float* W      = (const float*)d_in[1];
  const float* b_caps = (const float*)d_in[2];
  const float* gamma  = (const float*)d_in[3];
  const float* Wq     = (const float*)d_in[4];
  const float* bq     = (const float*)d_in[5];
  const float* Wk     = (const float*)d_in[6];
  const float* bk     = (const float*)d_in[7];
  const float* Wv_in  = (const float*)d_in[8];
  const float* bv_in  = (const float*)d_in[9];
  const float* Wo     = (const float*)d_in[10];
  const float* bo     = (const float*)d_in[11];
  const float* ln_g   = (const float*)d_in[12];
  const float* ln_b   = (const float*)d_in[13];
  float* out = (float*)d_out;
  float* ws  = (float*)d_ws;

  float* xpart = ws + OFF_XPART;
  float* v     = ws + OFF_V;
  float* Wv    = ws + OFF_WV;
  float* bv    = ws + OFF_BV;
  float* ctx   = ws + OFF_CTX;
  float* y     = ws + OFF_Y;
  float* cs    = ws + OFF_CS;
  float* csp   = ws + OFF_CSP;
  float* yp    = ws + OFF_YP;

  const int usePart = (ws_size >= WS_NEED_PARTIAL) ? 1 : 0;

  // iter 0: uniform coupling — only column sums of x needed
  k_xpart<<<dim3(kB, 16), 256, 0, stream>>>(x, xpart);
  k_sv<<<kB * kC, 64, 0, stream>>>(W, b_caps, xpart, y, cs, yp, csp, v, Wv, bv,
                                   /*mode=*/0, /*computeWv=*/1, /*accWv=*/0, 0);

  // routing pass 1: logits = u·v0 (= x·Wv + bv)
  if (!usePart) {
    hipMemsetAsync(y, 0, (size_t)kB * kC * kD * sizeof(float), stream);
    hipMemsetAsync(cs, 0, (size_t)kB * kC * sizeof(float), stream);
  }
  k_route<<<dim3(kB, kChunks), 256, 0, stream>>>(x, Wv, bv, y, cs, yp, csp, usePart);
  // v1 = squash(y·W + cs·b_caps); Wv += W·v1, bv += b_caps·v1  (b2 = u·(v0+v1))
  k_sv<<<kB * kC, 64, 0, stream>>>(W, b_caps, xpart, y, cs, yp, csp, v, Wv, bv,
                                   /*mode=*/1, /*computeWv=*/1, /*accWv=*/1, usePart ? kChunks : 0);

  // routing pass 2: logits = u·(v0+v1)
  if (!usePart) {
    hipMemsetAsync(y, 0, (size_t)kB * kC * kD * sizeof(float), stream);
    hipMemsetAsync(cs, 0, (size_t)kB * kC * sizeof(float), stream);
  }
  k_route<<<dim3(kB, kChunks), 256, 0, stream>>>(x, Wv, bv, y, cs, yp, csp, usePart);
  k_sv<<<kB * kC, 64, 0, stream>>>(W, b_caps, xpart, y, cs, yp, csp, v, Wv, bv,
                                   /*mode=*/1, /*computeWv=*/0, /*accWv=*/0, usePart ? kChunks : 0);

  // v now holds routed [B,C,H]
  k_mha<<<dim3(kB, kHeads), 256, 0, stream>>>(v, Wq, bq, Wk, bk, Wv_in, bv_in, ctx);
  k_final<<<kB * kC, 64, 0, stream>>>(ctx, Wo, bo, v, ln_g, ln_b, gamma, out);
}